// Round 8
// baseline (253.053 us; speedup 1.0000x reference)
//
#include <hip/hip_runtime.h>

// ---------------------------------------------------------------------------
// CrossAttention: B=8, T=S=1024, E=H=768, fp32 in/out, bf16 MFMA internally.
//
// Round 8: r7's register-pipelined block GEMM at BK=32: LDS per block
// 64KB -> 32KB (2x16KB double buffer) so 3 blocks/CU co-reside (r7 was
// capped at 2, measured 1.3 avg). Same barrier count per K, same LDS op
// count, half the staging registers. Swizzle: read slot quad^((l16>>1)&3)
// (r3/r5 verified 0-conflict); write side bank-balanced.
// ---------------------------------------------------------------------------

typedef __bf16 bf16x8 __attribute__((ext_vector_type(8)));
typedef float  f32x4  __attribute__((ext_vector_type(4)));

__device__ __forceinline__ unsigned short f2bf(float f) {
    unsigned int u = __float_as_uint(f);
    u += 0x7fffu + ((u >> 16) & 1u);   // RNE; inputs are finite
    return (unsigned short)(u >> 16);
}

// Block computes C[row0:row0+128, col0:col0+128].
// Ag = A + row0*K ([*,K] bf16 row-major); Bg = B^T + col0*K ([*,K]).
// Exactly one of Cf/Cb non-null. transC: store C^T as [b][H][S] (vt).
__device__ __forceinline__ void gemm_core(
    const unsigned short* __restrict__ Ag,
    const unsigned short* __restrict__ Bg,
    const int K,
    float* __restrict__ Cf, unsigned short* __restrict__ Cb,
    const long ldc, const int transC, const float* __restrict__ bias,
    const float scale, const long row0, const long col0)
{
    __shared__ __align__(16) unsigned short As[2][4096];   // [128][32] swizzled
    __shared__ __align__(16) unsigned short Bs[2][4096];

    const int tid  = threadIdx.x;
    const int lane = tid & 63;
    const int quad = lane >> 4;
    const int l16  = lane & 15;
    const int wave = tid >> 6;
    const int wm   = (wave >> 1) * 64;
    const int wn   = (wave & 1) * 64;

    // staging geometry (BK=32): chunk c = tid + h*256 -> row r = (tid>>2)+h*64,
    // k-chunk s = tid&3 (h-invariant), slot = s ^ ((r>>1)&3) (h-invariant).
    const int rbase = tid >> 2;                  // 0..63
    const int s     = tid & 3;
    const int slot  = s ^ ((rbase >> 1) & 3);
    const unsigned short* ga = Ag + (long)rbase * K + s * 8;
    const unsigned short* gb = Bg + (long)rbase * K + s * 8;
    const int lo = rbase * 32 + slot * 8;        // element offset in LDS tile

    f32x4 acc[4][4];
#pragma unroll
    for (int i = 0; i < 4; ++i)
#pragma unroll
        for (int j = 0; j < 4; ++j)
            acc[i][j] = f32x4{0.f, 0.f, 0.f, 0.f};

    // two staging sets, named scalars only (spill-proof, r7-verified)
    uint4 p0, p1, q0, q1;
    uint4 u0, u1, v0, v1;

#define LDA(h, k0) (*(const uint4*)(ga + (long)(h) * 64 * K + (k0)))
#define LDB(h, k0) (*(const uint4*)(gb + (long)(h) * 64 * K + (k0)))
#define STAGE_P(k0) { p0=LDA(0,k0); p1=LDA(1,k0); q0=LDB(0,k0); q1=LDB(1,k0); }
#define STAGE_U(k0) { u0=LDA(0,k0); u1=LDA(1,k0); v0=LDB(0,k0); v1=LDB(1,k0); }
#define COMMIT_P(buf) { *(uint4*)&As[buf][lo]=p0; *(uint4*)&As[buf][lo+2048]=p1; \
                        *(uint4*)&Bs[buf][lo]=q0; *(uint4*)&Bs[buf][lo+2048]=q1; }
#define COMMIT_U(buf) { *(uint4*)&As[buf][lo]=u0; *(uint4*)&As[buf][lo+2048]=u1; \
                        *(uint4*)&Bs[buf][lo]=v0; *(uint4*)&Bs[buf][lo+2048]=v1; }

    // LDS -> frags -> 16 MFMA (one k-step of 32)
    auto compute = [&](int buf) {
        bf16x8 af[4], bf[4];
        const int sl = (quad ^ ((l16 >> 1) & 3)) * 8;
#pragma unroll
        for (int i = 0; i < 4; ++i) {
            af[i] = *(const bf16x8*)&As[buf][(wm + i * 16 + l16) * 32 + sl];
            bf[i] = *(const bf16x8*)&Bs[buf][(wn + i * 16 + l16) * 32 + sl];
        }
#pragma unroll
        for (int i = 0; i < 4; ++i)
#pragma unroll
            for (int j = 0; j < 4; ++j)
                acc[i][j] = __builtin_amdgcn_mfma_f32_16x16x32_bf16(
                    af[i], bf[j], acc[i][j], 0, 0, 0);
    };

    const int nk = K >> 5;            // 24 or 32 — always even
    STAGE_P(0);
    COMMIT_P(0);
    STAGE_U(32);
    __syncthreads();

    for (int t = 0; t < nk; t += 2) {
        if (t + 2 < nk) STAGE_P((t + 2) << 5);   // prefetch t+2 (a full iter early)
        compute(0);                              // tile t
        COMMIT_U(1);                             // tile t+1 -> buf1
        __syncthreads();

        if (t + 3 < nk) STAGE_U((t + 3) << 5);   // prefetch t+3
        compute(1);                              // tile t+1
        if (t + 2 < nk) COMMIT_P(0);             // tile t+2 -> buf0
        __syncthreads();
    }
#undef LDA
#undef LDB
#undef STAGE_P
#undef STAGE_U
#undef COMMIT_P
#undef COMMIT_U

    // epilogue: C/D layout col=lane&15, row=quad*4+reg  [m89/m91 verified]
#pragma unroll
    for (int i = 0; i < 4; ++i) {
#pragma unroll
        for (int j = 0; j < 4; ++j) {
            const long r0 = row0 + wm + i * 16 + quad * 4;
            const long c  = col0 + wn + j * 16 + l16;
            const float bb = bias ? bias[c] : 0.0f;
#pragma unroll
            for (int r = 0; r < 4; ++r) {
                const float v = acc[i][j][r] * scale + bb;
                const long rr = r0 + r;
                if (Cb) {
                    if (transC) {
                        Cb[((rr >> 10) * 768 + c) * 1024 + (rr & 1023)] = f2bf(v);
                    } else {
                        Cb[rr * ldc + c] = f2bf(v);
                    }
                } else {
                    Cf[rr * ldc + c] = v;
                }
            }
        }
    }
}

// ---------------------------------------------------------------------------

__global__ __launch_bounds__(256, 3) void proj_qkv(
    const unsigned short* __restrict__ xb, const unsigned short* __restrict__ eb,
    const unsigned short* __restrict__ wqt, const unsigned short* __restrict__ wkt,
    const unsigned short* __restrict__ wvt,
    const float* __restrict__ bq, const float* __restrict__ bk,
    const float* __restrict__ bv,
    unsigned short* __restrict__ q, unsigned short* __restrict__ k,
    unsigned short* __restrict__ vt)
{
    const unsigned short *A, *Bt; const float* bias; unsigned short* C;
    int trans = 0;
    switch (blockIdx.z) {
        case 0:  A = xb; Bt = wqt; bias = bq; C = q;  break;
        case 1:  A = eb; Bt = wkt; bias = bk; C = k;  break;
        default: A = eb; Bt = wvt; bias = bv; C = vt; trans = 1; break;
    }
    const long row0 = (long)blockIdx.x * 128;
    const long col0 = (long)blockIdx.y * 128;
    gemm_core(A + row0 * 768, Bt + col0 * 768, 768,
              nullptr, C, 768, trans, bias, 1.0f, row0, col0);
}

__global__ __launch_bounds__(256, 3) void scores_gemm(
    const unsigned short* __restrict__ q, const unsigned short* __restrict__ k,
    float* __restrict__ sc, float scale)
{
    const long b    = blockIdx.z;
    const long row0 = (long)blockIdx.x * 128;    // within batch
    const long col0 = (long)blockIdx.y * 128;
    gemm_core(q + (b * 1024 + row0) * 768, k + b * 786432 + col0 * 768, 768,
              sc + b * 1048576, nullptr, 1024, 0, nullptr, scale, row0, col0);
}

__global__ __launch_bounds__(256, 3) void pv_gemm(
    const unsigned short* __restrict__ p, const unsigned short* __restrict__ vt,
    unsigned short* __restrict__ ao)
{
    const long b    = blockIdx.z;
    const long row0 = (long)blockIdx.x * 128;    // within batch
    const long col0 = (long)blockIdx.y * 128;
    gemm_core(p + (b * 1024 + row0) * 1024, vt + b * 786432 + col0 * 1024, 1024,
              nullptr, ao + b * 786432, 768, 0, nullptr, 1.0f, row0, col0);
}

__global__ __launch_bounds__(256, 3) void outproj_gemm(
    const unsigned short* __restrict__ ao, const unsigned short* __restrict__ wpt,
    float* __restrict__ out, const float* __restrict__ bp)
{
    const long row0 = (long)blockIdx.x * 128;
    const long col0 = (long)blockIdx.y * 128;
    gemm_core(ao + row0 * 768, wpt + col0 * 768, 768,
              out, nullptr, 768, 0, bp, 1.0f, row0, col0);
}

// ---------------------------------------------------------------------------

__global__ __launch_bounds__(256) void convert_inputs(
    const float* __restrict__ x, const float* __restrict__ enc,
    unsigned short* __restrict__ xb, unsigned short* __restrict__ eb, int nper)
{
    const int i = blockIdx.x * 256 + threadIdx.x;   // float4 index
    const bool second = (i >= nper);
    const int idx = second ? i - nper : i;
    const float4 v = second ? ((const float4*)enc)[idx] : ((const float4*)x)[idx];
    ushort4 o;
    o.x = f2bf(v.x); o.y = f2bf(v.y); o.z = f2bf(v.z); o.w = f2bf(v.w);
    if (second) ((ushort4*)eb)[idx] = o;
    else        ((ushort4*)xb)[idx] = o;
}

__global__ __launch_bounds__(256) void transpose_w(
    const float* __restrict__ w0, const float* __restrict__ w1,
    const float* __restrict__ w2, const float* __restrict__ w3,
    unsigned short* __restrict__ o0, unsigned short* __restrict__ o1,
    unsigned short* __restrict__ o2, unsigned short* __restrict__ o3)
{
    const float* w; unsigned short* o;
    switch (blockIdx.z) {
        case 0:  w = w0; o = o0; break;
        case 1:  w = w1; o = o1; break;
        case 2:  w = w2; o = o2; break;
        default: w = w3; o = o3; break;
    }
    __shared__ float t[32][33];
    const int tx = threadIdx.x & 31;
    const int ty = threadIdx.x >> 5;          // 0..7
    const int k0 = blockIdx.x * 32;
    const int n0 = blockIdx.y * 32;
#pragma unroll
    for (int i = 0; i < 4; ++i)
        t[ty + i * 8][tx] = w[(long)(k0 + ty + i * 8) * 768 + n0 + tx];
    __syncthreads();
#pragma unroll
    for (int i = 0; i < 4; ++i)
        o[(long)(n0 + ty + i * 8) * 768 + k0 + tx] = f2bf(t[tx][ty + i * 8]);
}

__global__ __launch_bounds__(256) void softmax_rows(
    const float* __restrict__ S, unsigned short* __restrict__ P)
{
    const long row = blockIdx.x;                 // 8192 rows of 1024
    const float* s = S + row * 1024;
    unsigned short* p = P + row * 1024;
    const int tid  = threadIdx.x;
    const int lane = tid & 63;
    const int wave = tid >> 6;

    float4 v = ((const float4*)s)[tid];
    float m = fmaxf(fmaxf(v.x, v.y), fmaxf(v.z, v.w));
#pragma unroll
    for (int off = 32; off > 0; off >>= 1)
        m = fmaxf(m, __shfl_xor(m, off));
    __shared__ float redm[4], reds[4];
    if (lane == 0) redm[wave] = m;
    __syncthreads();
    m = fmaxf(fmaxf(redm[0], redm[1]), fmaxf(redm[2], redm[3]));

    const float e0 = __expf(v.x - m), e1 = __expf(v.y - m);
    const float e2 = __expf(v.z - m), e3 = __expf(v.w - m);
    float sum = e0 + e1 + e2 + e3;
#pragma unroll
    for (int off = 32; off > 0; off >>= 1)
        sum += __shfl_xor(sum, off);
    if (lane == 0) reds[wave] = sum;
    __syncthreads();
    const float inv = 1.0f / (reds[0] + reds[1] + reds[2] + reds[3]);

    ushort4 o;
    o.x = f2bf(e0 * inv); o.y = f2bf(e1 * inv);
    o.z = f2bf(e2 * inv); o.w = f2bf(e3 * inv);
    ((ushort4*)p)[tid] = o;
}

// ---------------------------------------------------------------------------

extern "C" void kernel_launch(void* const* d_in, const int* in_sizes, int n_in,
                              void* d_out, int out_size, void* d_ws, size_t ws_size,
                              hipStream_t stream) {
    const float* x   = (const float*)d_in[0];
    const float* enc = (const float*)d_in[1];
    const float* Wq  = (const float*)d_in[2];
    const float* bq  = (const float*)d_in[3];
    const float* Wk  = (const float*)d_in[4];
    const float* bk  = (const float*)d_in[5];
    const float* Wv  = (const float*)d_in[6];
    const float* bv  = (const float*)d_in[7];
    const float* Wp  = (const float*)d_in[8];
    const float* bp  = (const float*)d_in[9];
    float* out = (float*)d_out;

    // workspace layout (bytes); peak need ~101.2 MB
    char* ws = (char*)d_ws;
    unsigned short* xb  = (unsigned short*)(ws + 0);         // 12582912
    unsigned short* eb  = (unsigned short*)(ws + 12582912);  // 12582912
    unsigned short* q   = (unsigned short*)(ws + 25165824);  // 12582912
    unsigned short* k   = (unsigned short*)(ws + 37748736);  // 12582912
    unsigned short* vt  = (unsigned short*)(ws + 50331648);  // 12582912 [B][H][S]
    unsigned short* wqt = (unsigned short*)(ws + 62914560);  // 1179648
    unsigned short* wkt = (unsigned short*)(ws + 64094208);  // 1179648
    unsigned short* wvt = (unsigned short*)(ws + 65273856);  // 1179648
    unsigned short* wpt = (unsigned short*)(ws + 66453504);  // 1179648
    float*          sc  = (float*)(ws + 67633152);           // 33554432 fp32 scores
    unsigned short* p   = (unsigned short*)(ws + 0);         // 16777216, overlays xb/eb (dead)
    unsigned short* ao  = (unsigned short*)(ws + 67633152);  // 12582912, overlays sc (dead)

    const float scale = 0.03608439182435161f;  // 1/sqrt(768)

    // 1. fp32 -> bf16 for x and encoder_out
    convert_inputs<<<12288, 256, 0, stream>>>(x, enc, xb, eb, 1572864);

    // 2. W^T bf16 for all four weights
    transpose_w<<<dim3(24, 24, 4), 256, 0, stream>>>(Wq, Wk, Wv, Wp, wqt, wkt, wvt, wpt);

    // 3. q/k/v projections: 128x128 tiles
    proj_qkv<<<dim3(64, 6, 3), 256, 0, stream>>>(xb, eb, wqt, wkt, wvt, bq, bk, bv, q, k, vt);

    // 4. scores = q k^T * scale (fp32)
    scores_gemm<<<dim3(8, 8, 8), 256, 0, stream>>>(q, k, sc, scale);

    // 5. softmax rows -> bf16 P
    softmax_rows<<<8192, 256, 0, stream>>>(sc, p);

    // 6. ao = P @ V
    pv_gemm<<<dim3(8, 6, 8), 256, 0, stream>>>(p, vt, ao);

    // 7. out = ao @ Wp + bp
    outproj_gemm<<<dim3(64, 6, 1), 256, 0, stream>>>(ao, wpt, out, bp);
}

// Round 9
// 240.515 us; speedup vs baseline: 1.0521x; 1.0521x over previous
//
#include <hip/hip_runtime.h>

// ---------------------------------------------------------------------------
// CrossAttention: B=8, T=S=1024, E=H=768, fp32 in/out, bf16 MFMA internally.
//
// Round 9: AITER-style DMA double-buffered GEMM. 128x128 tile, BK=64,
// 4 waves. global_load_lds stages tiles into FOUR separate static
// __shared__ arrays (As0/As1/Bs0/Bs1 -> alias analysis can distinguish);
// synchronization is hand-rolled: s_waitcnt vmcnt(8) (waits current
// buffer only, next tile's 8 loads stay in flight) + raw s_barrier
// (no __syncthreads -> no forced vmcnt(0) drain). No ds_writes at all.
// Swizzle: source k-chunk j=(lane&7)^((lane>>3)&7) at linear slot, read
// slot (quad+h*4)^(l16&7) — same bank pattern as r7 (measured 0 conflicts).
// ---------------------------------------------------------------------------

typedef __bf16 bf16x8 __attribute__((ext_vector_type(8)));
typedef float  f32x4  __attribute__((ext_vector_type(4)));

#define WAIT_VM8 __builtin_amdgcn_s_waitcnt(0x0F78)   // vmcnt(8), lgkm/exp nowait
#define WAIT_VM0 __builtin_amdgcn_s_waitcnt(0x0F70)   // vmcnt(0)
#define BAR      __builtin_amdgcn_s_barrier()

__device__ __forceinline__ unsigned short f2bf(float f) {
    unsigned int u = __float_as_uint(f);
    u += 0x7fffu + ((u >> 16) & 1u);   // RNE; inputs are finite
    return (unsigned short)(u >> 16);
}

__device__ __forceinline__ void async_copy16(const void* g, void* s) {
    __builtin_amdgcn_global_load_lds(
        (const __attribute__((address_space(1))) void*)g,
        (__attribute__((address_space(3))) void*)s, 16, 0, 0);
}

// Block computes C[row0:row0+128, col0:col0+128].
// Ag = A + row0*K ([*,K] bf16 row-major); Bg = B^T + col0*K ([*,K]).
// Exactly one of Cf/Cb non-null. transC: store C^T as [b][H][S] (vt).
__device__ __forceinline__ void gemm_core(
    const unsigned short* __restrict__ Ag,
    const unsigned short* __restrict__ Bg,
    const int K,
    float* __restrict__ Cf, unsigned short* __restrict__ Cb,
    const long ldc, const int transC, const float* __restrict__ bias,
    const float scale, const long row0, const long col0)
{
    __shared__ __align__(16) unsigned short As0[8192];   // [128][64] swizzled
    __shared__ __align__(16) unsigned short As1[8192];
    __shared__ __align__(16) unsigned short Bs0[8192];
    __shared__ __align__(16) unsigned short Bs1[8192];

    const int tid  = threadIdx.x;
    const int lane = tid & 63;
    const int quad = lane >> 4;
    const int l16  = lane & 15;
    const int wv   = tid >> 6;
    const int wm   = (wv >> 1) * 64;
    const int wn   = (wv & 1) * 64;

    // DMA staging: chunk c = wv*256 + h*64 + lane covers row r=c>>3, linear
    // slot s=lane&7; source k-chunk j = s ^ (r&7) = (lane&7)^((lane>>3)&7).
    const int j8 = ((lane & 7) ^ ((lane >> 3) & 7)) * 8;   // src k-offset, elems
    const int rb = wv * 32 + (lane >> 3);                  // row for h=0
    const unsigned short* sa_src = Ag + (long)rb * K + j8;
    const unsigned short* sb_src = Bg + (long)rb * K + j8;
    const int dbase = (wv * 256 + lane) * 8;               // LDS dst elems, h=0

    f32x4 acc[4][4];
#pragma unroll
    for (int i = 0; i < 4; ++i)
#pragma unroll
        for (int j = 0; j < 4; ++j)
            acc[i][j] = f32x4{0.f, 0.f, 0.f, 0.f};

    // one tile = 8 DMA instructions per thread (4 A + 4 B)
    auto stage = [&](unsigned short* dA, unsigned short* dB, int k0) {
#pragma unroll
        for (int h = 0; h < 4; ++h) {
            async_copy16(sa_src + (long)(h * 8) * K + k0, &dA[dbase + h * 512]);
            async_copy16(sb_src + (long)(h * 8) * K + k0, &dB[dbase + h * 512]);
        }
    };

    // 32 MFMA per wave per tile (two k-halves of 32)
    auto compute = [&](const unsigned short* sA, const unsigned short* sB) {
#pragma unroll
        for (int h = 0; h < 2; ++h) {
            bf16x8 af[4], bf[4];
            const int sl = ((quad + h * 4) ^ (l16 & 7)) * 8;
#pragma unroll
            for (int i = 0; i < 4; ++i) {
                af[i] = *(const bf16x8*)&sA[(wm + i * 16 + l16) * 64 + sl];
                bf[i] = *(const bf16x8*)&sB[(wn + i * 16 + l16) * 64 + sl];
            }
#pragma unroll
            for (int i = 0; i < 4; ++i)
#pragma unroll
                for (int j = 0; j < 4; ++j)
                    acc[i][j] = __builtin_amdgcn_mfma_f32_16x16x32_bf16(
                        af[i], bf[j], acc[i][j], 0, 0, 0);
        }
    };

    const int nk = K >> 6;            // 12 or 16: even, >= 4
    stage(As0, Bs0, 0);               // tile 0 -> buf0   (8 loads)
    stage(As1, Bs1, 64);              // tile 1 -> buf1   (8 loads)
    int k0 = 128;

    for (int t = 0; t < nk - 2; t += 2) {
        WAIT_VM8; BAR;                // buf0 (tile t) landed everywhere
        compute(As0, Bs0);
        BAR;                          // all waves done reading buf0
        stage(As0, Bs0, k0); k0 += 64;        // tile t+2 -> buf0

        WAIT_VM8; BAR;                // buf1 (tile t+1) landed
        compute(As1, Bs1);
        BAR;
        stage(As1, Bs1, k0); k0 += 64;        // tile t+3 -> buf1
    }
    WAIT_VM8; BAR;                    // tile nk-2
    compute(As0, Bs0);
    WAIT_VM0; BAR;                    // tile nk-1
    compute(As1, Bs1);

    // epilogue: C/D layout col=lane&15, row=quad*4+reg  [m89/m91 verified]
#pragma unroll
    for (int i = 0; i < 4; ++i) {
#pragma unroll
        for (int j = 0; j < 4; ++j) {
            const long r0 = row0 + wm + i * 16 + quad * 4;
            const long c  = col0 + wn + j * 16 + l16;
            const float bb = bias ? bias[c] : 0.0f;
#pragma unroll
            for (int r = 0; r < 4; ++r) {
                const float v = acc[i][j][r] * scale + bb;
                const long rr = r0 + r;
                if (Cb) {
                    if (transC) {
                        Cb[((rr >> 10) * 768 + c) * 1024 + (rr & 1023)] = f2bf(v);
                    } else {
                        Cb[rr * ldc + c] = f2bf(v);
                    }
                } else {
                    Cf[rr * ldc + c] = v;
                }
            }
        }
    }
}

// ---------------------------------------------------------------------------

__global__ __launch_bounds__(256, 2) void proj_qkv(
    const unsigned short* __restrict__ xb, const unsigned short* __restrict__ eb,
    const unsigned short* __restrict__ wqt, const unsigned short* __restrict__ wkt,
    const unsigned short* __restrict__ wvt,
    const float* __restrict__ bq, const float* __restrict__ bk,
    const float* __restrict__ bv,
    unsigned short* __restrict__ q, unsigned short* __restrict__ k,
    unsigned short* __restrict__ vt)
{
    const unsigned short *A, *Bt; const float* bias; unsigned short* C;
    int trans = 0;
    switch (blockIdx.z) {
        case 0:  A = xb; Bt = wqt; bias = bq; C = q;  break;
        case 1:  A = eb; Bt = wkt; bias = bk; C = k;  break;
        default: A = eb; Bt = wvt; bias = bv; C = vt; trans = 1; break;
    }
    const long row0 = (long)blockIdx.x * 128;
    const long col0 = (long)blockIdx.y * 128;
    gemm_core(A + row0 * 768, Bt + col0 * 768, 768,
              nullptr, C, 768, trans, bias, 1.0f, row0, col0);
}

__global__ __launch_bounds__(256, 2) void scores_gemm(
    const unsigned short* __restrict__ q, const unsigned short* __restrict__ k,
    float* __restrict__ sc, float scale)
{
    const long b    = blockIdx.z;
    const long row0 = (long)blockIdx.x * 128;    // within batch
    const long col0 = (long)blockIdx.y * 128;
    gemm_core(q + (b * 1024 + row0) * 768, k + b * 786432 + col0 * 768, 768,
              sc + b * 1048576, nullptr, 1024, 0, nullptr, scale, row0, col0);
}

__global__ __launch_bounds__(256, 2) void pv_gemm(
    const unsigned short* __restrict__ p, const unsigned short* __restrict__ vt,
    unsigned short* __restrict__ ao)
{
    const long b    = blockIdx.z;
    const long row0 = (long)blockIdx.x * 128;    // within batch
    const long col0 = (long)blockIdx.y * 128;
    gemm_core(p + (b * 1024 + row0) * 1024, vt + b * 786432 + col0 * 1024, 1024,
              nullptr, ao + b * 786432, 768, 0, nullptr, 1.0f, row0, col0);
}

__global__ __launch_bounds__(256, 2) void outproj_gemm(
    const unsigned short* __restrict__ ao, const unsigned short* __restrict__ wpt,
    float* __restrict__ out, const float* __restrict__ bp)
{
    const long row0 = (long)blockIdx.x * 128;
    const long col0 = (long)blockIdx.y * 128;
    gemm_core(ao + row0 * 768, wpt + col0 * 768, 768,
              out, nullptr, 768, 0, bp, 1.0f, row0, col0);
}

// ---------------------------------------------------------------------------

__global__ __launch_bounds__(256) void convert_inputs(
    const float* __restrict__ x, const float* __restrict__ enc,
    unsigned short* __restrict__ xb, unsigned short* __restrict__ eb, int nper)
{
    const int i = blockIdx.x * 256 + threadIdx.x;   // float4 index
    const bool second = (i >= nper);
    const int idx = second ? i - nper : i;
    const float4 v = second ? ((const float4*)enc)[idx] : ((const float4*)x)[idx];
    ushort4 o;
    o.x = f2bf(v.x); o.y = f2bf(v.y); o.z = f2bf(v.z); o.w = f2bf(v.w);
    if (second) ((ushort4*)eb)[idx] = o;
    else        ((ushort4*)xb)[idx] = o;
}

__global__ __launch_bounds__(256) void transpose_w(
    const float* __restrict__ w0, const float* __restrict__ w1,
    const float* __restrict__ w2, const float* __restrict__ w3,
    unsigned short* __restrict__ o0, unsigned short* __restrict__ o1,
    unsigned short* __restrict__ o2, unsigned short* __restrict__ o3)
{
    const float* w; unsigned short* o;
    switch (blockIdx.z) {
        case 0:  w = w0; o = o0; break;
        case 1:  w = w1; o = o1; break;
        case 2:  w = w2; o = o2; break;
        default: w = w3; o = o3; break;
    }
    __shared__ float t[32][33];
    const int tx = threadIdx.x & 31;
    const int ty = threadIdx.x >> 5;          // 0..7
    const int k0 = blockIdx.x * 32;
    const int n0 = blockIdx.y * 32;
#pragma unroll
    for (int i = 0; i < 4; ++i)
        t[ty + i * 8][tx] = w[(long)(k0 + ty + i * 8) * 768 + n0 + tx];
    __syncthreads();
#pragma unroll
    for (int i = 0; i < 4; ++i)
        o[(long)(n0 + ty + i * 8) * 768 + k0 + tx] = f2bf(t[tx][ty + i * 8]);
}

__global__ __launch_bounds__(256) void softmax_rows(
    const float* __restrict__ S, unsigned short* __restrict__ P)
{
    const long row = blockIdx.x;                 // 8192 rows of 1024
    const float* s = S + row * 1024;
    unsigned short* p = P + row * 1024;
    const int tid  = threadIdx.x;
    const int lane = tid & 63;
    const int wave = tid >> 6;

    float4 v = ((const float4*)s)[tid];
    float m = fmaxf(fmaxf(v.x, v.y), fmaxf(v.z, v.w));
#pragma unroll
    for (int off = 32; off > 0; off >>= 1)
        m = fmaxf(m, __shfl_xor(m, off));
    __shared__ float redm[4], reds[4];
    if (lane == 0) redm[wave] = m;
    __syncthreads();
    m = fmaxf(fmaxf(redm[0], redm[1]), fmaxf(redm[2], redm[3]));

    const float e0 = __expf(v.x - m), e1 = __expf(v.y - m);
    const float e2 = __expf(v.z - m), e3 = __expf(v.w - m);
    float sum = e0 + e1 + e2 + e3;
#pragma unroll
    for (int off = 32; off > 0; off >>= 1)
        sum += __shfl_xor(sum, off);
    if (lane == 0) reds[wave] = sum;
    __syncthreads();
    const float inv = 1.0f / (reds[0] + reds[1] + reds[2] + reds[3]);

    ushort4 o;
    o.x = f2bf(e0 * inv); o.y = f2bf(e1 * inv);
    o.z = f2bf(e2 * inv); o.w = f2bf(e3 * inv);
    ((ushort4*)p)[tid] = o;
}

// ---------------------------------------------------------------------------

extern "C" void kernel_launch(void* const* d_in, const int* in_sizes, int n_in,
                              void* d_out, int out_size, void* d_ws, size_t ws_size,
                              hipStream_t stream) {
    const float* x   = (const float*)d_in[0];
    const float* enc = (const float*)d_in[1];
    const float* Wq  = (const float*)d_in[2];
    const float* bq  = (const float*)d_in[3];
    const float* Wk  = (const float*)d_in[4];
    const float* bk  = (const float*)d_in[5];
    const float* Wv  = (const float*)d_in[6];
    const float* bv  = (const float*)d_in[7];
    const float* Wp  = (const float*)d_in[8];
    const float* bp  = (const float*)d_in[9];
    float* out = (float*)d_out;

    // workspace layout (bytes); peak need ~101.2 MB
    char* ws = (char*)d_ws;
    unsigned short* xb  = (unsigned short*)(ws + 0);         // 12582912
    unsigned short* eb  = (unsigned short*)(ws + 12582912);  // 12582912
    unsigned short* q   = (unsigned short*)(ws + 25165824);  // 12582912
    unsigned short* k   = (unsigned short*)(ws + 37748736);  // 12582912
    unsigned short* vt  = (unsigned short*)(ws + 50331648);  // 12582912 [B][H][S]
    unsigned short* wqt = (unsigned short*)(ws + 62914560);  // 1179648
    unsigned short* wkt = (unsigned short*)(ws + 64094208);  // 1179648
    unsigned short* wvt = (unsigned short*)(ws + 65273856);  // 1179648
    unsigned short* wpt = (unsigned short*)(ws + 66453504);  // 1179648
    float*          sc  = (float*)(ws + 67633152);           // 33554432 fp32 scores
    unsigned short* p   = (unsigned short*)(ws + 0);         // 16777216, overlays xb/eb (dead)
    unsigned short* ao  = (unsigned short*)(ws + 67633152);  // 12582912, overlays sc (dead)

    const float scale = 0.03608439182435161f;  // 1/sqrt(768)

    // 1. fp32 -> bf16 for x and encoder_out
    convert_inputs<<<12288, 256, 0, stream>>>(x, enc, xb, eb, 1572864);

    // 2. W^T bf16 for all four weights
    transpose_w<<<dim3(24, 24, 4), 256, 0, stream>>>(Wq, Wk, Wv, Wp, wqt, wkt, wvt, wpt);

    // 3. q/k/v projections: 128x128 tiles
    proj_qkv<<<dim3(64, 6, 3), 256, 0, stream>>>(xb, eb, wqt, wkt, wvt, bq, bk, bv, q, k, vt);

    // 4. scores = q k^T * scale (fp32)
    scores_gemm<<<dim3(8, 8, 8), 256, 0, stream>>>(q, k, sc, scale);

    // 5. softmax rows -> bf16 P
    softmax_rows<<<8192, 256, 0, stream>>>(sc, p);

    // 6. ao = P @ V
    pv_gemm<<<dim3(8, 6, 8), 256, 0, stream>>>(p, vt, ao);

    // 7. out = ao @ Wp + bp
    outproj_gemm<<<dim3(64, 6, 1), 256, 0, stream>>>(ao, wpt, out, bp);
}